// Round 5
// baseline (107.231 us; speedup 1.0000x reference)
//
#include <hip/hip_runtime.h>
#include <hip/hip_fp16.h>

#define D_VOCAB 262
#define D_EMB   128
#define KW      5
#define NCHAR   16
#define NROW    (D_VOCAB * KW)       // 1310 (v,k) rows
#define CH      16                   // channels per chunk
#define NCHUNK  (D_EMB / CH)         // 8
#define CHUNK_HALFS (NROW * CH)      // 20960 halfs / chunk = 41,920 B
#define LROW2   10                   // LDS row stride in half2 (40 B: 16 data + 8 pad)
#define SEQ_PER_BLOCK 256

// d_ws layout:
//   Pc at offset 0       : 8 chunks x 41,920 B = 335,360 B (chunked fp16 table)
//       Pc[c][(v*5+k)*16 + ch]  for global channel o = c*16+ch
//   Wt at offset 335,872 : 640*128 floats = 327,680 B (transposed conv_w)

// ---------------------------------------------------------------------------
// Stage 1: Wt[(k*128+o)*128 + i] = conv_w[o*640 + i*5 + k]. Coalesced reads,
// scattered dword writes (320 KB, L2 absorbs). No LDS, no barriers.
// ---------------------------------------------------------------------------
__global__ __launch_bounds__(256) void transpose_w_kernel(
    const float* __restrict__ cw, float* __restrict__ Wt) {
  const int gid = blockIdx.x * 256 + threadIdx.x;   // 0..81919
  const float val = cw[gid];
  const int o = gid / 640;
  const int r = gid - o * 640;
  const int i = r / 5;
  const int k = r - i * 5;
  Wt[(k * D_EMB + o) * D_EMB + i] = val;
}

// ---------------------------------------------------------------------------
// Stage 2: P[v][k][o] = sum_i emb[v][i]*Wt[k*128+o][i], written in CHUNKED
// layout (see d_ws map). One lane per (v,ko): 32 float4 loads of L2-resident
// Wt + 128 FMA. 2620 waves, no barriers.
// ---------------------------------------------------------------------------
__global__ __launch_bounds__(256) void compute_P_kernel(
    const float* __restrict__ emb, const float* __restrict__ Wt,
    __half* __restrict__ Pc) {
  const int wave = threadIdx.x >> 6;
  const int lane = threadIdx.x & 63;
  const int w = blockIdx.x * 4 + wave;      // 0..2619
  const int v = w / 10;                     // vocab id (wave-uniform)
  const int ko = (w - v * 10) * 64 + lane;  // k*128 + o

  const float* er = emb + v * D_EMB;
  const float4* wt = (const float4*)(Wt + ko * D_EMB);
  float acc = 0.f;
#pragma unroll 8
  for (int i4 = 0; i4 < 32; ++i4) {
    const float4 wv = wt[i4];
    acc += er[i4 * 4 + 0] * wv.x + er[i4 * 4 + 1] * wv.y +
           er[i4 * 4 + 2] * wv.z + er[i4 * 4 + 3] * wv.w;
  }
  const int k = ko >> 7;
  const int o = ko & 127;
  Pc[(size_t)(o >> 4) * CHUNK_HALFS + (v * KW + k) * CH + (o & 15)] =
      __float2half(acc);
}

// ---------------------------------------------------------------------------
// Main: block = (chunk c, 256 seqs). Stage chunk into LDS (rows padded to
// 40 B so row-start banks spread), then 16 waves x 16 seqs/wave x 4 lanes/seq
// x 4 ch/lane. Per (j,k): one ds_read_b64 (k folds into the offset imm) +
// 2x v_pk_add_f16. Max in fp32 at slot completion only. No global P traffic
// in the hot loop.
// ---------------------------------------------------------------------------
__global__ __launch_bounds__(1024, 8) void conv_char_main_kernel(
    const int* __restrict__ ids, const __half* __restrict__ Pc,
    const float* __restrict__ bias, float* __restrict__ out, int n_seq) {
  __shared__ __half2 lds[NROW * LROW2];   // 13,100 half2 = 52,400 B

  const int t = threadIdx.x;
  const int c = blockIdx.x & (NCHUNK - 1);
  const int seqbase = (blockIdx.x >> 3) * SEQ_PER_BLOCK;

  // ---- stage chunk c (41,920 B) into LDS, re-padding rows 32 B -> 40 B ----
  const int4* src = (const int4*)(Pc + (size_t)c * CHUNK_HALFS);
  for (int t4 = t; t4 < CHUNK_HALFS / 8; t4 += 1024) {   // 2620 16-B pieces
    const int4 v = src[t4];
    const int row = t4 >> 1;
    const int dst = row * LROW2 + (t4 & 1) * 4;          // half2 index
    *(int2*)&lds[dst]     = make_int2(v.x, v.y);
    *(int2*)&lds[dst + 2] = make_int2(v.z, v.w);
  }
  __syncthreads();

  const int wave = t >> 6;
  const int lane = t & 63;
  const int q = lane & 3;                       // channel quarter
  const int wseq = seqbase + wave * 16;         // this wave's first seq
  const int n = wseq + (lane >> 2);             // this group's seq

  // 256 ids for the wave's 16 seqs, coalesced int4 (lane holds 4 chars)
  int4 myids = make_int4(0, 0, 0, 0);
  if (wseq + (lane >> 2) < n_seq)               // lane's 4 ids are in-bounds
    myids = ((const int4*)(ids + (size_t)wseq * NCHAR))[lane];
  const int ida[4] = {myids.x, myids.y, myids.z, myids.w};

  const __half2 hz = __float2half2_rn(0.f);
  __half2 win[5][2];
#pragma unroll
  for (int s = 0; s < 5; ++s) { win[s][0] = hz; win[s][1] = hz; }
  float vmax[4] = {-1e30f, -1e30f, -1e30f, -1e30f};

#pragma unroll
  for (int j = 0; j < NCHAR; ++j) {
    // id of (group's seq, char j): lane g*4 + j/4, component j%4 (j is const)
    const int idv = __shfl(ida[j & 3], (lane & 60) + (j >> 2));
    const __half2* rp = &lds[idv * (KW * LROW2) + q * 2];
#pragma unroll
    for (int k = 0; k < KW; ++k) {
      const int cc = j + 2 - k;                 // output position fed
      if (cc >= 0 && cc < NCHAR) {
        const int2 rv = *(const int2*)(rp + k * LROW2);   // ds_read_b64
        const __half2 a = *(const __half2*)&rv.x;
        const __half2 b = *(const __half2*)&rv.y;
        __half2* ws = win[cc % 5];
        ws[0] = __hadd2(ws[0], a);
        ws[1] = __hadd2(ws[1], b);
      }
    }
    if (j >= 2) {                               // y[j-2] complete
      const int s = (j - 2) % 5;
      const float2 f0 = __half22float2(win[s][0]);
      const float2 f1 = __half22float2(win[s][1]);
      vmax[0] = fmaxf(vmax[0], f0.x); vmax[1] = fmaxf(vmax[1], f0.y);
      vmax[2] = fmaxf(vmax[2], f1.x); vmax[3] = fmaxf(vmax[3], f1.y);
      win[s][0] = hz; win[s][1] = hz;
    }
  }
#pragma unroll
  for (int cc = 14; cc < 16; ++cc) {
    const int s = cc % 5;
    const float2 f0 = __half22float2(win[s][0]);
    const float2 f1 = __half22float2(win[s][1]);
    vmax[0] = fmaxf(vmax[0], f0.x); vmax[1] = fmaxf(vmax[1], f0.y);
    vmax[2] = fmaxf(vmax[2], f1.x); vmax[3] = fmaxf(vmax[3], f1.y);
  }

  if (n < n_seq) {
    const float4 bv = *(const float4*)(bias + c * CH + q * 4);
    float4 r;
    r.x = vmax[0] + bv.x; r.y = vmax[1] + bv.y;
    r.z = vmax[2] + bv.z; r.w = vmax[3] + bv.w;
    *(float4*)(out + (size_t)n * D_EMB + c * CH + q * 4) = r;
  }
}

// ---------------------------------------------------------------------------
// Inputs: d_in[0] ids (B*W*C int32), d_in[1] lengths (unused),
//         d_in[2] emb (262x128 f32), d_in[3] conv_w (128x128x5 f32),
//         d_in[4] conv_b (128 f32).  Output: (B*W*128) f32.
// ---------------------------------------------------------------------------
extern "C" void kernel_launch(void* const* d_in, const int* in_sizes, int n_in,
                              void* d_out, int out_size, void* d_ws, size_t ws_size,
                              hipStream_t stream) {
  const int*   input = (const int*)d_in[0];
  const float* emb   = (const float*)d_in[2];
  const float* cw    = (const float*)d_in[3];
  const float* cb    = (const float*)d_in[4];
  float* out = (float*)d_out;

  __half* Pc = (__half*)d_ws;
  float*  Wt = (float*)((char*)d_ws + 335872);

  const int n_seq = in_sizes[0] / NCHAR;   // B*W = 32768

  transpose_w_kernel<<<320, 256, 0, stream>>>(cw, Wt);    // 81,920 elems
  compute_P_kernel<<<655, 256, 0, stream>>>(emb, Wt, Pc); // 2,620 waves

  const int seq_blocks = (n_seq + SEQ_PER_BLOCK - 1) / SEQ_PER_BLOCK;  // 128
  conv_char_main_kernel<<<seq_blocks * NCHUNK, 1024, 0, stream>>>(
      input, Pc, cb, out, n_seq);
}